// Round 2
// baseline (495.412 us; speedup 1.0000x reference)
//
#include <hip/hip_runtime.h>
#include <cstdint>
#include <cstddef>

#define B_N 32
#define A_N 32768
#define G_N 50
#define C_N 22
#define BA  (B_N * A_N)

// ---------------- helpers ----------------

__device__ __forceinline__ float iou_one(float gx0, float gy0, float gx1, float gy1, float ga,
                                         float ax0, float ay0, float ax1, float ay1, float aa) {
    // mirror reference op order: inter / (a0 + a1 - inter + 1e-5)
    float lx = fmaxf(gx0, ax0), ly = fmaxf(gy0, ay0);
    float rx = fminf(gx1, ax1), ry = fminf(gy1, ay1);
    float iw = fmaxf(rx - lx, 0.0f), ih = fmaxf(ry - ly, 0.0f);
    float inter = iw * ih;
    return inter / (ga + aa - inter + 1e-5f);
}

__device__ __forceinline__ unsigned int f2key(float x) {
    unsigned int u = __float_as_uint(x);
    return (u & 0x80000000u) ? ~u : (u | 0x80000000u);
}

// ---------------- kernels ----------------

// zero the small accumulator header (hdr[0..127] covers hdr + num_pos_row + neg_sum)
__global__ void init_kernel(float* hdr) {
    if (threadIdx.x < 128) hdr[threadIdx.x] = 0.0f;
}

// one block per (b,g): argmax over anchors of IoU (first occurrence on ties -> smallest a)
__global__ __launch_bounds__(256) void best_prior_kernel(
        const float* __restrict__ gts, const int* __restrict__ counts,
        const float* __restrict__ anchors, int* __restrict__ bp_idx) {
    int bg = blockIdx.x;
    int b = bg / G_N, g = bg % G_N;
    if (g >= counts[b]) return;   // uniform exit, no barrier hazard
    const float* gtb = gts + (size_t)(b * G_N + g) * 5;
    float gx0 = gtb[0], gy0 = gtb[1], gx1 = gtb[2], gy1 = gtb[3];
    float ga = fmaxf(gx1 - gx0, 0.0f) * fmaxf(gy1 - gy0, 0.0f);
    float best = -1e30f; int bidx = 0;
    for (int a = threadIdx.x; a < A_N; a += 256) {
        float4 an = reinterpret_cast<const float4*>(anchors)[a];
        float aa = fmaxf(an.z - an.x, 0.0f) * fmaxf(an.w - an.y, 0.0f);
        float iou = iou_one(gx0, gy0, gx1, gy1, ga, an.x, an.y, an.z, an.w, aa);
        if (iou > best) { best = iou; bidx = a; }   // strict > keeps smallest a
    }
    __shared__ float sv[256];
    __shared__ int   si[256];
    sv[threadIdx.x] = best; si[threadIdx.x] = bidx;
    __syncthreads();
    for (int s = 128; s > 0; s >>= 1) {
        if (threadIdx.x < s) {
            float v2 = sv[threadIdx.x + s]; int i2 = si[threadIdx.x + s];
            float v1 = sv[threadIdx.x];     int i1 = si[threadIdx.x];
            if (v2 > v1 || (v2 == v1 && i2 < i1)) { sv[threadIdx.x] = v2; si[threadIdx.x] = i2; }
        }
        __syncthreads();
    }
    if (threadIdx.x == 0) bp_idx[bg] = si[0];
}

// one thread per (b,a): argmax over g (first occurrence on ties -> smallest g)
__global__ __launch_bounds__(256) void best_target_kernel(
        const float* __restrict__ gts, const int* __restrict__ counts,
        const float* __restrict__ anchors,
        float* __restrict__ bt_iou, unsigned char* __restrict__ bt_idx) {
    int i = blockIdx.x * 256 + threadIdx.x;
    int b = i >> 15;
    int a = i & (A_N - 1);
    float4 an = reinterpret_cast<const float4*>(anchors)[a];
    float aa = fmaxf(an.z - an.x, 0.0f) * fmaxf(an.w - an.y, 0.0f);
    int cnt = counts[b];
    const float* gtb = gts + (size_t)b * G_N * 5;
    float best = -2.0f; int bidx = 0;
    for (int g = 0; g < cnt; ++g) {
        float gx0 = gtb[g * 5 + 0], gy0 = gtb[g * 5 + 1];
        float gx1 = gtb[g * 5 + 2], gy1 = gtb[g * 5 + 3];
        float ga = fmaxf(gx1 - gx0, 0.0f) * fmaxf(gy1 - gy0, 0.0f);
        float iou = iou_one(gx0, gy0, gx1, gy1, ga, an.x, an.y, an.z, an.w, aa);
        if (iou > best) { best = iou; bidx = g; }
    }
    bt_iou[i] = best;
    bt_idx[i] = (unsigned char)bidx;
}

// forced matches: sequential over g per batch (ascending -> last-wins like scatter)
__global__ void force_match_kernel(const int* __restrict__ counts, const int* __restrict__ bp_idx,
                                   float* __restrict__ bt_iou, unsigned char* __restrict__ bt_idx) {
    int b = threadIdx.x;
    if (b >= B_N) return;
    int cnt = counts[b];
    for (int g = 0; g < cnt; ++g) {
        int p = bp_idx[b * G_N + g];
        bt_idx[(size_t)b * A_N + p] = (unsigned char)g;
        bt_iou[(size_t)b * A_N + p] = 2.0f;
    }
}

// labels + smooth-L1 localisation loss + per-row positive counts
__global__ __launch_bounds__(256) void label_loc_kernel(
        const float* __restrict__ gts, const float* __restrict__ anchors,
        const float* __restrict__ pred_loc,
        const float* __restrict__ bt_iou, const unsigned char* __restrict__ bt_idx,
        unsigned char* __restrict__ labels, int* __restrict__ num_pos_row,
        float* __restrict__ loc_sum) {
    int i = blockIdx.x * 256 + threadIdx.x;
    int b = i >> 15;
    int a = i & (A_N - 1);
    float iou = bt_iou[i];
    int gi = bt_idx[i];
    int label = 0;
    if (!(iou < 0.5f)) label = (int)gts[(size_t)(b * G_N + gi) * 5 + 4];
    labels[i] = (unsigned char)label;
    bool pos = label > 0;
    float contrib = 0.0f;
    if (pos) {
        float4 an = reinterpret_cast<const float4*>(anchors)[a];
        float acx = (an.x + an.z) * 0.5f, acy = (an.y + an.w) * 0.5f;
        float aw = an.z - an.x, ah = an.w - an.y;
        const float* gtb = gts + (size_t)(b * G_N + gi) * 5;
        float cx = (gtb[0] + gtb[2]) * 0.5f, cy = (gtb[1] + gtb[3]) * 0.5f;
        float w = gtb[2] - gtb[0], h = gtb[3] - gtb[1];
        float l0 = ((cx - acx) / aw) / 0.1f;
        float l1 = ((cy - acy) / ah) / 0.1f;
        float l2 = logf(fmaxf(w / aw, 1e-8f)) / 0.2f;
        float l3 = logf(fmaxf(h / ah, 1e-8f)) / 0.2f;
        float4 p = reinterpret_cast<const float4*>(pred_loc)[i];
        float d0 = fabsf(p.x - l0), d1 = fabsf(p.y - l1);
        float d2 = fabsf(p.z - l2), d3 = fabsf(p.w - l3);
        contrib  = (d0 < 1.0f ? 0.5f * d0 * d0 : d0 - 0.5f);
        contrib += (d1 < 1.0f ? 0.5f * d1 * d1 : d1 - 0.5f);
        contrib += (d2 < 1.0f ? 0.5f * d2 * d2 : d2 - 0.5f);
        contrib += (d3 < 1.0f ? 0.5f * d3 * d3 : d3 - 0.5f);
    }
    // block reduction: loc sum + pos count (block lies entirely inside one b)
    unsigned long long bal = __ballot(pos);
    for (int o = 32; o > 0; o >>= 1) contrib += __shfl_down(contrib, o, 64);
    __shared__ float swf[4];
    __shared__ int   swi[4];
    int wid = threadIdx.x >> 6, lane = threadIdx.x & 63;
    if (lane == 0) { swf[wid] = contrib; swi[wid] = __popcll(bal); }
    __syncthreads();
    if (threadIdx.x == 0) {
        float s = swf[0] + swf[1] + swf[2] + swf[3];
        int   c = swi[0] + swi[1] + swi[2] + swi[3];
        if (s != 0.0f) atomicAdd(loc_sum, s);
        if (c) atomicAdd(&num_pos_row[b], c);
    }
}

// log-softmax per row: mining array (bg_loss, -inf for pos) + pos CE sum
// FP order mirrors jax.nn.log_softmax: logp[j] = (v[j]-m) - log(sum(exp(v-m)))
__global__ __launch_bounds__(256) void cls_kernel(
        const float* __restrict__ conf, const unsigned char* __restrict__ labels,
        float* __restrict__ mining, float* __restrict__ pos_ce_sum) {
    int i = blockIdx.x * 256 + threadIdx.x;
    float v[C_N];
    const float2* c2 = reinterpret_cast<const float2*>(conf + (size_t)i * C_N);
    #pragma unroll
    for (int j = 0; j < C_N / 2; ++j) { float2 t = c2[j]; v[2 * j] = t.x; v[2 * j + 1] = t.y; }
    float m = v[0];
    #pragma unroll
    for (int j = 1; j < C_N; ++j) m = fmaxf(m, v[j]);
    float s = 0.0f;
    #pragma unroll
    for (int j = 0; j < C_N; ++j) s += expf(v[j] - m);
    float ls = logf(s);
    int lab = labels[i];
    float ce_pos = 0.0f;
    if (lab > 0) {
        float vl = v[0];
        #pragma unroll
        for (int j = 1; j < C_N; ++j) vl = (j == lab) ? v[j] : vl;  // register select, no scratch
        ce_pos = ls - (vl - m);                 // -log_prob[lab], exact ref order
        mining[i] = __int_as_float(0xFF800000); // -inf
    } else {
        mining[i] = ls - (v[0] - m);            // bg_loss, exact ref order
    }
    for (int o = 32; o > 0; o >>= 1) ce_pos += __shfl_down(ce_pos, o, 64);
    __shared__ float swf[4];
    int wid = threadIdx.x >> 6, lane = threadIdx.x & 63;
    if (lane == 0) swf[wid] = ce_pos;
    __syncthreads();
    if (threadIdx.x == 0) {
        float t = swf[0] + swf[1] + swf[2] + swf[3];
        if (t != 0.0f) atomicAdd(pos_ce_sum, t);
    }
}

// per-row radix select: sum of top-k bg_loss among negatives, k = 3*num_pos
__global__ __launch_bounds__(256) void select_kernel(
        const float* __restrict__ mining, const int* __restrict__ num_pos_row,
        float* __restrict__ neg_sum) {
    int b = blockIdx.x;
    int np = num_pos_row[b];
    long long k = 3LL * np;
    int num_neg = A_N - np;
    int k_eff = (int)((k < (long long)num_neg) ? k : (long long)num_neg);
    if (k_eff <= 0) { if (threadIdx.x == 0) neg_sum[b] = 0.0f; return; }
    const float* row = mining + (size_t)b * A_N;

    __shared__ unsigned int hist[256];
    __shared__ unsigned int s_prefix;
    __shared__ int s_krem;
    unsigned int prefix = 0;
    int krem = k_eff;

    for (int pass = 0; pass < 4; ++pass) {
        int shift = 24 - 8 * pass;
        hist[threadIdx.x] = 0;
        __syncthreads();
        for (int a = threadIdx.x; a < A_N; a += 256) {
            unsigned int u = f2key(row[a]);
            bool match = (pass == 0) || ((u >> (shift + 8)) == prefix);
            if (match) atomicAdd(&hist[(u >> shift) & 0xFFu], 1u);
        }
        __syncthreads();
        if (threadIdx.x == 0) {
            int cum = 0, chosen = 0;
            for (int bin = 255; bin >= 0; --bin) {
                int c = (int)hist[bin];
                if (cum + c >= krem) { chosen = bin; break; }
                cum += c;
            }
            s_prefix = (prefix << 8) | (unsigned int)chosen;
            s_krem = krem - cum;
        }
        __syncthreads();
        prefix = s_prefix;
        krem = s_krem;
        __syncthreads();
    }

    unsigned int kth = prefix;   // exact 32-bit key of kth-largest
    float sum = 0.0f;
    for (int a = threadIdx.x; a < A_N; a += 256) {
        float x = row[a];
        if (f2key(x) > kth) sum += x;
    }
    for (int o = 32; o > 0; o >>= 1) sum += __shfl_down(sum, o, 64);
    __shared__ float swf[4];
    int wid = threadIdx.x >> 6, lane = threadIdx.x & 63;
    if (lane == 0) swf[wid] = sum;
    __syncthreads();
    if (threadIdx.x == 0) {
        float tot = swf[0] + swf[1] + swf[2] + swf[3];
        float vk = __uint_as_float((kth & 0x80000000u) ? (kth ^ 0x80000000u) : ~kth);
        neg_sum[b] = tot + (float)krem * vk;   // ties share the identical value
    }
}

__global__ void final_kernel(const float* __restrict__ hdr, const int* __restrict__ num_pos_row,
                             const float* __restrict__ neg_sum, float* __restrict__ out) {
    if (threadIdx.x != 0) return;
    int tot = 0;
    for (int b = 0; b < B_N; ++b) tot += num_pos_row[b];
    float npos = fmaxf(1.0f, (float)tot);
    float negs = 0.0f;
    for (int b = 0; b < B_N; ++b) negs += neg_sum[b];
    out[0] = hdr[0] / (npos * 4.0f);            // localisation loss
    out[1] = (hdr[1] + negs) / (npos * 4.0f);   // classification loss
}

// ---------------- launch ----------------

extern "C" void kernel_launch(void* const* d_in, const int* in_sizes, int n_in,
                              void* d_out, int out_size, void* d_ws, size_t ws_size,
                              hipStream_t stream) {
    const float* conf     = (const float*)d_in[0];
    const float* pred_loc = (const float*)d_in[1];
    const float* gts      = (const float*)d_in[2];
    const int*   counts   = (const int*)d_in[3];
    const float* anchors  = (const float*)d_in[4];
    float* out = (float*)d_out;

    char* ws = (char*)d_ws;
    float* hdr          = (float*)ws;                       // [0]=loc_sum, [1]=pos_ce
    int*   num_pos_row  = (int*)(ws + 8);                   // 32 ints
    float* neg_sum      = (float*)(ws + 8 + 32 * 4);        // 32 floats
    int*   bp_idx       = (int*)(ws + 512);                 // B*G ints (6400B)
    float* bt_iou       = (float*)(ws + 8192);              // BA floats (4MB)
    unsigned char* bt_idx = (unsigned char*)(ws + 8192 + (size_t)4 * BA);  // BA bytes
    unsigned char* labels = (unsigned char*)(ws + 8192 + (size_t)5 * BA);  // BA bytes
    float* mining       = (float*)(ws + 8192 + (size_t)6 * BA);            // BA floats

    init_kernel<<<1, 128, 0, stream>>>(hdr);
    best_prior_kernel<<<B_N * G_N, 256, 0, stream>>>(gts, counts, anchors, bp_idx);
    best_target_kernel<<<BA / 256, 256, 0, stream>>>(gts, counts, anchors, bt_iou, bt_idx);
    force_match_kernel<<<1, 64, 0, stream>>>(counts, bp_idx, bt_iou, bt_idx);
    label_loc_kernel<<<BA / 256, 256, 0, stream>>>(gts, anchors, pred_loc, bt_iou, bt_idx,
                                                   labels, num_pos_row, hdr);
    cls_kernel<<<BA / 256, 256, 0, stream>>>(conf, labels, mining, hdr + 1);
    select_kernel<<<B_N, 256, 0, stream>>>(mining, num_pos_row, neg_sum);
    final_kernel<<<1, 64, 0, stream>>>(hdr, num_pos_row, neg_sum, out);
}

// Round 3
// 384.581 us; speedup vs baseline: 1.2882x; 1.2882x over previous
//
#include <hip/hip_runtime.h>
#include <cstdint>
#include <cstddef>

#define B_N 32
#define A_N 32768
#define G_N 50
#define C_N 22
#define BA  (B_N * A_N)

#define SEL_CAP 4096   // survivor list capacity (LDS); fallback to global rescan if exceeded

// ---------------- helpers ----------------

__device__ __forceinline__ float iou_one(float gx0, float gy0, float gx1, float gy1, float ga,
                                         float ax0, float ay0, float ax1, float ay1, float aa) {
    // mirror reference op order: inter / (a0 + a1 - inter + 1e-5)
    float lx = fmaxf(gx0, ax0), ly = fmaxf(gy0, ay0);
    float rx = fminf(gx1, ax1), ry = fminf(gy1, ay1);
    float iw = fmaxf(rx - lx, 0.0f), ih = fmaxf(ry - ly, 0.0f);
    float inter = iw * ih;
    return inter / (ga + aa - inter + 1e-5f);
}

__device__ __forceinline__ unsigned int f2key(float x) {
    unsigned int u = __float_as_uint(x);
    return (u & 0x80000000u) ? ~u : (u | 0x80000000u);
}

__device__ __forceinline__ float key2f(unsigned int k) {
    return __uint_as_float((k & 0x80000000u) ? (k & 0x7FFFFFFFu) : ~k);
}

// ---------------- kernels ----------------

// zero the small accumulator header (hdr[0..127] covers hdr + num_pos_row + neg_sum)
__global__ void init_kernel(float* hdr) {
    if (threadIdx.x < 128) hdr[threadIdx.x] = 0.0f;
}

// one block per (b,g): argmax over anchors of IoU (first occurrence on ties -> smallest a)
__global__ __launch_bounds__(256) void best_prior_kernel(
        const float* __restrict__ gts, const int* __restrict__ counts,
        const float* __restrict__ anchors, int* __restrict__ bp_idx) {
    int bg = blockIdx.x;
    int b = bg / G_N, g = bg % G_N;
    if (g >= counts[b]) return;   // uniform exit, no barrier hazard
    const float* gtb = gts + (size_t)(b * G_N + g) * 5;
    float gx0 = gtb[0], gy0 = gtb[1], gx1 = gtb[2], gy1 = gtb[3];
    float ga = fmaxf(gx1 - gx0, 0.0f) * fmaxf(gy1 - gy0, 0.0f);
    float best = -1e30f; int bidx = 0;
    for (int a = threadIdx.x; a < A_N; a += 256) {
        float4 an = reinterpret_cast<const float4*>(anchors)[a];
        float aa = fmaxf(an.z - an.x, 0.0f) * fmaxf(an.w - an.y, 0.0f);
        float iou = iou_one(gx0, gy0, gx1, gy1, ga, an.x, an.y, an.z, an.w, aa);
        if (iou > best) { best = iou; bidx = a; }   // strict > keeps smallest a
    }
    __shared__ float sv[256];
    __shared__ int   si[256];
    sv[threadIdx.x] = best; si[threadIdx.x] = bidx;
    __syncthreads();
    for (int s = 128; s > 0; s >>= 1) {
        if (threadIdx.x < s) {
            float v2 = sv[threadIdx.x + s]; int i2 = si[threadIdx.x + s];
            float v1 = sv[threadIdx.x];     int i1 = si[threadIdx.x];
            if (v2 > v1 || (v2 == v1 && i2 < i1)) { sv[threadIdx.x] = v2; si[threadIdx.x] = i2; }
        }
        __syncthreads();
    }
    if (threadIdx.x == 0) bp_idx[bg] = si[0];
}

// one thread per (b,a): argmax over g (first occurrence on ties -> smallest g)
// b is uniform per block -> stage gt boxes + areas in LDS
__global__ __launch_bounds__(256) void best_target_kernel(
        const float* __restrict__ gts, const int* __restrict__ counts,
        const float* __restrict__ anchors,
        float* __restrict__ bt_iou, unsigned char* __restrict__ bt_idx) {
    int i = blockIdx.x * 256 + threadIdx.x;
    int b = blockIdx.x >> 7;            // 128 blocks per batch row
    int a = i & (A_N - 1);
    int cnt = counts[b];
    __shared__ float sg[G_N][5];        // x0,y0,x1,y1,area
    if (threadIdx.x < G_N) {
        int g = threadIdx.x;
        const float* gtb = gts + (size_t)(b * G_N + g) * 5;
        float x0 = gtb[0], y0 = gtb[1], x1 = gtb[2], y1 = gtb[3];
        sg[g][0] = x0; sg[g][1] = y0; sg[g][2] = x1; sg[g][3] = y1;
        sg[g][4] = fmaxf(x1 - x0, 0.0f) * fmaxf(y1 - y0, 0.0f);
    }
    __syncthreads();
    float4 an = reinterpret_cast<const float4*>(anchors)[a];
    float aa = fmaxf(an.z - an.x, 0.0f) * fmaxf(an.w - an.y, 0.0f);
    float best = -2.0f; int bidx = 0;
    for (int g = 0; g < cnt; ++g) {
        float iou = iou_one(sg[g][0], sg[g][1], sg[g][2], sg[g][3], sg[g][4],
                            an.x, an.y, an.z, an.w, aa);
        if (iou > best) { best = iou; bidx = g; }
    }
    bt_iou[i] = best;
    bt_idx[i] = (unsigned char)bidx;
}

// forced matches: sequential over g per batch (ascending -> last-wins like scatter)
__global__ void force_match_kernel(const int* __restrict__ counts, const int* __restrict__ bp_idx,
                                   float* __restrict__ bt_iou, unsigned char* __restrict__ bt_idx) {
    int b = threadIdx.x;
    if (b >= B_N) return;
    int cnt = counts[b];
    for (int g = 0; g < cnt; ++g) {
        int p = bp_idx[b * G_N + g];
        bt_idx[(size_t)b * A_N + p] = (unsigned char)g;
        bt_iou[(size_t)b * A_N + p] = 2.0f;
    }
}

// labels + smooth-L1 localisation loss + per-row positive counts
__global__ __launch_bounds__(256) void label_loc_kernel(
        const float* __restrict__ gts, const float* __restrict__ anchors,
        const float* __restrict__ pred_loc,
        const float* __restrict__ bt_iou, const unsigned char* __restrict__ bt_idx,
        unsigned char* __restrict__ labels, int* __restrict__ num_pos_row,
        float* __restrict__ loc_sum) {
    int i = blockIdx.x * 256 + threadIdx.x;
    int b = i >> 15;
    int a = i & (A_N - 1);
    float iou = bt_iou[i];
    int gi = bt_idx[i];
    int label = 0;
    if (!(iou < 0.5f)) label = (int)gts[(size_t)(b * G_N + gi) * 5 + 4];
    labels[i] = (unsigned char)label;
    bool pos = label > 0;
    float contrib = 0.0f;
    if (pos) {
        float4 an = reinterpret_cast<const float4*>(anchors)[a];
        float acx = (an.x + an.z) * 0.5f, acy = (an.y + an.w) * 0.5f;
        float aw = an.z - an.x, ah = an.w - an.y;
        const float* gtb = gts + (size_t)(b * G_N + gi) * 5;
        float cx = (gtb[0] + gtb[2]) * 0.5f, cy = (gtb[1] + gtb[3]) * 0.5f;
        float w = gtb[2] - gtb[0], h = gtb[3] - gtb[1];
        float l0 = ((cx - acx) / aw) / 0.1f;
        float l1 = ((cy - acy) / ah) / 0.1f;
        float l2 = logf(fmaxf(w / aw, 1e-8f)) / 0.2f;
        float l3 = logf(fmaxf(h / ah, 1e-8f)) / 0.2f;
        float4 p = reinterpret_cast<const float4*>(pred_loc)[i];
        float d0 = fabsf(p.x - l0), d1 = fabsf(p.y - l1);
        float d2 = fabsf(p.z - l2), d3 = fabsf(p.w - l3);
        contrib  = (d0 < 1.0f ? 0.5f * d0 * d0 : d0 - 0.5f);
        contrib += (d1 < 1.0f ? 0.5f * d1 * d1 : d1 - 0.5f);
        contrib += (d2 < 1.0f ? 0.5f * d2 * d2 : d2 - 0.5f);
        contrib += (d3 < 1.0f ? 0.5f * d3 * d3 : d3 - 0.5f);
    }
    unsigned long long bal = __ballot(pos);
    for (int o = 32; o > 0; o >>= 1) contrib += __shfl_down(contrib, o, 64);
    __shared__ float swf[4];
    __shared__ int   swi[4];
    int wid = threadIdx.x >> 6, lane = threadIdx.x & 63;
    if (lane == 0) { swf[wid] = contrib; swi[wid] = __popcll(bal); }
    __syncthreads();
    if (threadIdx.x == 0) {
        float s = swf[0] + swf[1] + swf[2] + swf[3];
        int   c = swi[0] + swi[1] + swi[2] + swi[3];
        if (s != 0.0f) atomicAdd(loc_sum, s);
        if (c) atomicAdd(&num_pos_row[b], c);
    }
}

// log-softmax per row: mining array (bg_loss, -inf for pos) + pos CE sum
// FP order mirrors jax.nn.log_softmax: logp[j] = (v[j]-m) - log(sum(exp(v-m)))
__global__ __launch_bounds__(256) void cls_kernel(
        const float* __restrict__ conf, const unsigned char* __restrict__ labels,
        float* __restrict__ mining, float* __restrict__ pos_ce_sum) {
    int i = blockIdx.x * 256 + threadIdx.x;
    float v[C_N];
    const float2* c2 = reinterpret_cast<const float2*>(conf + (size_t)i * C_N);
    #pragma unroll
    for (int j = 0; j < C_N / 2; ++j) { float2 t = c2[j]; v[2 * j] = t.x; v[2 * j + 1] = t.y; }
    float m = v[0];
    #pragma unroll
    for (int j = 1; j < C_N; ++j) m = fmaxf(m, v[j]);
    float s = 0.0f;
    #pragma unroll
    for (int j = 0; j < C_N; ++j) s += expf(v[j] - m);
    float ls = logf(s);
    int lab = labels[i];
    float ce_pos = 0.0f;
    if (lab > 0) {
        float vl = v[0];
        #pragma unroll
        for (int j = 1; j < C_N; ++j) vl = (j == lab) ? v[j] : vl;
        ce_pos = ls - (vl - m);
        mining[i] = __int_as_float(0xFF800000); // -inf
    } else {
        mining[i] = ls - (v[0] - m);
    }
    for (int o = 32; o > 0; o >>= 1) ce_pos += __shfl_down(ce_pos, o, 64);
    __shared__ float swf[4];
    int wid = threadIdx.x >> 6, lane = threadIdx.x & 63;
    if (lane == 0) swf[wid] = ce_pos;
    __syncthreads();
    if (threadIdx.x == 0) {
        float t = swf[0] + swf[1] + swf[2] + swf[3];
        if (t != 0.0f) atomicAdd(pos_ce_sum, t);
    }
}

// ---- radix select support: suffix-scan over packed-u16 histogram, pick bin + rank ----
// hist: nwords u32 words, each = two u16 bins {lo = bin 2t, hi = bin 2t+1}
// Finds highest bin such that count of bins >= it reaches krem; writes bin and residual rank.
__device__ __forceinline__ void scan_pick(unsigned* hist, int nwords,
                                          unsigned* sA, unsigned* sB,
                                          int krem, int* s_bin, int* s_krem) {
    int t = threadIdx.x;
    unsigned lo = 0, hi = 0;
    if (t < nwords) { unsigned w = hist[t]; lo = w & 0xFFFFu; hi = w >> 16; }
    sA[t] = lo + hi;
    __syncthreads();
    unsigned* src = sA; unsigned* dst = sB;
    for (int d = 1; d < 1024; d <<= 1) {
        unsigned v = src[t] + ((t + d < 1024) ? src[t + d] : 0u);
        dst[t] = v;
        __syncthreads();
        unsigned* tmp = src; src = dst; dst = tmp;
    }
    unsigned incl = src[t];
    unsigned incl_next = (t < 1023) ? src[t + 1] : 0u;
    unsigned uk = (unsigned)krem;
    if (incl >= uk && incl_next < uk) {     // unique crossing thread
        unsigned cum = incl_next;
        if (cum + hi >= uk) { *s_bin = 2 * t + 1; *s_krem = (int)(uk - cum); }
        else                { *s_bin = 2 * t;     *s_krem = (int)(uk - cum - hi); }
    }
    __syncthreads();
}

// per-row 3-level (11/11/10 bit) histogram select: sum of top-k bg_loss, k = 3*num_pos
__global__ __launch_bounds__(1024) void select_kernel(
        const float* __restrict__ mining, const int* __restrict__ num_pos_row,
        float* __restrict__ neg_sum) {
    int b = blockIdx.x;
    int tid = threadIdx.x;
    int np = num_pos_row[b];
    long long k = 3LL * np;
    int num_neg = A_N - np;
    int k_eff = (int)((k < (long long)num_neg) ? k : (long long)num_neg);
    if (k_eff <= 0) { if (tid == 0) neg_sum[b] = 0.0f; return; }   // uniform exit
    const float4* row4 = reinterpret_cast<const float4*>(mining + (size_t)b * A_N);

    __shared__ unsigned hist[1024];     // 2048 u16 bins packed
    __shared__ unsigned sA[1024], sB[1024];
    __shared__ unsigned surv[SEL_CAP];
    __shared__ int s_n1, s_bin, s_krem;
    __shared__ float swf[16];

    // ---- level 1: bits [31:21] (2048 bins) ----
    hist[tid] = 0;
    if (tid == 0) s_n1 = 0;
    __syncthreads();
    #pragma unroll
    for (int it = 0; it < A_N / 4 / 1024; ++it) {
        float4 v = row4[tid + it * 1024];
        unsigned k0 = f2key(v.x), k1 = f2key(v.y), k2 = f2key(v.z), k3 = f2key(v.w);
        unsigned b0 = k0 >> 21, b1 = k1 >> 21, b2 = k2 >> 21, b3 = k3 >> 21;
        atomicAdd(&hist[b0 >> 1], (b0 & 1) ? 65536u : 1u);
        atomicAdd(&hist[b1 >> 1], (b1 & 1) ? 65536u : 1u);
        atomicAdd(&hist[b2 >> 1], (b2 & 1) ? 65536u : 1u);
        atomicAdd(&hist[b3 >> 1], (b3 & 1) ? 65536u : 1u);
    }
    __syncthreads();
    scan_pick(hist, 1024, sA, sB, k_eff, &s_bin, &s_krem);
    unsigned bin1 = (unsigned)s_bin;
    int krem1 = s_krem;
    __syncthreads();

    // ---- pass 2: sum strictly-above bins + collect survivors of bin1 ----
    float sum_sel = 0.0f;
    #pragma unroll
    for (int it = 0; it < A_N / 4 / 1024; ++it) {
        float4 v = row4[tid + it * 1024];
        float xs[4] = {v.x, v.y, v.z, v.w};
        #pragma unroll
        for (int e = 0; e < 4; ++e) {
            unsigned key = f2key(xs[e]);
            unsigned t11 = key >> 21;
            if (t11 > bin1) sum_sel += xs[e];
            else if (t11 == bin1) {
                int p = atomicAdd(&s_n1, 1);
                if (p < SEL_CAP) surv[p] = key;
            }
        }
    }
    __syncthreads();
    int n1 = s_n1;
    bool in_lds = (n1 <= SEL_CAP);

    // ---- level 2: bits [20:10] (2048 bins) among survivors ----
    hist[tid] = 0;
    __syncthreads();
    if (in_lds) {
        for (int i = tid; i < n1; i += 1024) {
            unsigned bin = (surv[i] >> 10) & 0x7FFu;
            atomicAdd(&hist[bin >> 1], (bin & 1) ? 65536u : 1u);
        }
    } else {
        for (int it = 0; it < A_N / 4 / 1024; ++it) {
            float4 v = row4[tid + it * 1024];
            float xs[4] = {v.x, v.y, v.z, v.w};
            for (int e = 0; e < 4; ++e) {
                unsigned key = f2key(xs[e]);
                if ((key >> 21) == bin1) {
                    unsigned bin = (key >> 10) & 0x7FFu;
                    atomicAdd(&hist[bin >> 1], (bin & 1) ? 65536u : 1u);
                }
            }
        }
    }
    __syncthreads();
    scan_pick(hist, 1024, sA, sB, krem1, &s_bin, &s_krem);
    unsigned prefix22 = (bin1 << 11) | (unsigned)s_bin;
    int krem2 = s_krem;
    __syncthreads();

    // ---- level 3: bits [9:0] (1024 bins) ----
    hist[tid] = 0;
    __syncthreads();
    if (in_lds) {
        for (int i = tid; i < n1; i += 1024) {
            unsigned key = surv[i];
            if ((key >> 10) == prefix22) {
                unsigned bin = key & 0x3FFu;
                atomicAdd(&hist[bin >> 1], (bin & 1) ? 65536u : 1u);
            }
        }
    } else {
        for (int it = 0; it < A_N / 4 / 1024; ++it) {
            float4 v = row4[tid + it * 1024];
            float xs[4] = {v.x, v.y, v.z, v.w};
            for (int e = 0; e < 4; ++e) {
                unsigned key = f2key(xs[e]);
                if ((key >> 10) == prefix22) {
                    unsigned bin = key & 0x3FFu;
                    atomicAdd(&hist[bin >> 1], (bin & 1) ? 65536u : 1u);
                }
            }
        }
    }
    __syncthreads();
    scan_pick(hist, 512, sA, sB, krem2, &s_bin, &s_krem);
    unsigned kth = (prefix22 << 10) | (unsigned)s_bin;
    int krem3 = s_krem;
    __syncthreads();

    // ---- final: add survivors strictly above kth ----
    if (in_lds) {
        for (int i = tid; i < n1; i += 1024) {
            unsigned key = surv[i];
            if (key > kth) sum_sel += key2f(key);
        }
    } else {
        for (int it = 0; it < A_N / 4 / 1024; ++it) {
            float4 v = row4[tid + it * 1024];
            float xs[4] = {v.x, v.y, v.z, v.w};
            for (int e = 0; e < 4; ++e) {
                unsigned key = f2key(xs[e]);
                if ((key >> 21) == bin1 && key > kth) sum_sel += xs[e];
            }
        }
    }
    // block reduce
    for (int o = 32; o > 0; o >>= 1) sum_sel += __shfl_down(sum_sel, o, 64);
    int wid = tid >> 6, lane = tid & 63;
    if (lane == 0) swf[wid] = sum_sel;
    __syncthreads();
    if (tid == 0) {
        float tot = 0.0f;
        #pragma unroll
        for (int w = 0; w < 16; ++w) tot += swf[w];
        neg_sum[b] = tot + (float)krem3 * key2f(kth);   // ties share the identical value
    }
}

__global__ void final_kernel(const float* __restrict__ hdr, const int* __restrict__ num_pos_row,
                             const float* __restrict__ neg_sum, float* __restrict__ out) {
    if (threadIdx.x != 0) return;
    int tot = 0;
    for (int b = 0; b < B_N; ++b) tot += num_pos_row[b];
    float npos = fmaxf(1.0f, (float)tot);
    float negs = 0.0f;
    for (int b = 0; b < B_N; ++b) negs += neg_sum[b];
    out[0] = hdr[0] / (npos * 4.0f);            // localisation loss
    out[1] = (hdr[1] + negs) / (npos * 4.0f);   // classification loss
}

// ---------------- launch ----------------

extern "C" void kernel_launch(void* const* d_in, const int* in_sizes, int n_in,
                              void* d_out, int out_size, void* d_ws, size_t ws_size,
                              hipStream_t stream) {
    const float* conf     = (const float*)d_in[0];
    const float* pred_loc = (const float*)d_in[1];
    const float* gts      = (const float*)d_in[2];
    const int*   counts   = (const int*)d_in[3];
    const float* anchors  = (const float*)d_in[4];
    float* out = (float*)d_out;

    char* ws = (char*)d_ws;
    float* hdr          = (float*)ws;                       // [0]=loc_sum, [1]=pos_ce
    int*   num_pos_row  = (int*)(ws + 8);                   // 32 ints
    float* neg_sum      = (float*)(ws + 8 + 32 * 4);        // 32 floats
    int*   bp_idx       = (int*)(ws + 512);                 // B*G ints (6400B)
    float* bt_iou       = (float*)(ws + 8192);              // BA floats (4MB)
    unsigned char* bt_idx = (unsigned char*)(ws + 8192 + (size_t)4 * BA);  // BA bytes
    unsigned char* labels = (unsigned char*)(ws + 8192 + (size_t)5 * BA);  // BA bytes
    float* mining       = (float*)(ws + 8192 + (size_t)6 * BA);            // BA floats

    init_kernel<<<1, 128, 0, stream>>>(hdr);
    best_prior_kernel<<<B_N * G_N, 256, 0, stream>>>(gts, counts, anchors, bp_idx);
    best_target_kernel<<<BA / 256, 256, 0, stream>>>(gts, counts, anchors, bt_iou, bt_idx);
    force_match_kernel<<<1, 64, 0, stream>>>(counts, bp_idx, bt_iou, bt_idx);
    label_loc_kernel<<<BA / 256, 256, 0, stream>>>(gts, anchors, pred_loc, bt_iou, bt_idx,
                                                   labels, num_pos_row, hdr);
    cls_kernel<<<BA / 256, 256, 0, stream>>>(conf, labels, mining, hdr + 1);
    select_kernel<<<B_N, 1024, 0, stream>>>(mining, num_pos_row, neg_sum);
    final_kernel<<<1, 64, 0, stream>>>(hdr, num_pos_row, neg_sum, out);
}

// Round 4
// 301.245 us; speedup vs baseline: 1.6445x; 1.2766x over previous
//
#include <hip/hip_runtime.h>
#include <cstdint>
#include <cstddef>

#define B_N 32
#define A_N 32768
#define G_N 50
#define C_N 22
#define BA  (B_N * A_N)

#define GC 4
#define NCHUNK ((G_N + GC - 1) / GC)   // 13

#define SEL_CAP 4096   // survivor list capacity (LDS); fallback to global rescan if exceeded

// ---------------- helpers ----------------

__device__ __forceinline__ float iou_one(float gx0, float gy0, float gx1, float gy1, float ga,
                                         float ax0, float ay0, float ax1, float ay1, float aa) {
    // mirror reference op order: inter / (a0 + a1 - inter + 1e-5)
    float lx = fmaxf(gx0, ax0), ly = fmaxf(gy0, ay0);
    float rx = fminf(gx1, ax1), ry = fminf(gy1, ay1);
    float iw = fmaxf(rx - lx, 0.0f), ih = fmaxf(ry - ly, 0.0f);
    float inter = iw * ih;
    return inter / (ga + aa - inter + 1e-5f);
}

__device__ __forceinline__ unsigned int f2key(float x) {
    unsigned int u = __float_as_uint(x);
    return (u & 0x80000000u) ? ~u : (u | 0x80000000u);
}

__device__ __forceinline__ float key2f(unsigned int k) {
    return __uint_as_float((k & 0x80000000u) ? (k & 0x7FFFFFFFu) : ~k);
}

// ---------------- kernels ----------------

// zero 128 words: loc_part[32] | ce_part[32] | num_pos_row[32] | neg_sum[32]
__global__ void init_kernel(float* hdr) {
    if (threadIdx.x < 128) hdr[threadIdx.x] = 0.0f;
}

// block = (b, g-chunk of GC): argmax over anchors of IoU for GC gts at once
// (first occurrence on ties -> smallest a; anchors float4 load reused GC times)
__global__ __launch_bounds__(256) void best_prior_kernel(
        const float* __restrict__ gts, const int* __restrict__ counts,
        const float* __restrict__ anchors, int* __restrict__ bp_idx) {
    int b  = blockIdx.x / NCHUNK;
    int ch = blockIdx.x % NCHUNK;
    int g0 = ch * GC;
    int cnt = counts[b];
    if (g0 >= cnt) return;                 // uniform exit
    int ng = cnt - g0; if (ng > GC) ng = GC;
    __shared__ float sg[GC][5];
    if (threadIdx.x < (unsigned)ng) {
        int g = g0 + threadIdx.x;
        const float* gtb = gts + (size_t)(b * G_N + g) * 5;
        float x0 = gtb[0], y0 = gtb[1], x1 = gtb[2], y1 = gtb[3];
        sg[threadIdx.x][0] = x0; sg[threadIdx.x][1] = y0;
        sg[threadIdx.x][2] = x1; sg[threadIdx.x][3] = y1;
        sg[threadIdx.x][4] = fmaxf(x1 - x0, 0.0f) * fmaxf(y1 - y0, 0.0f);
    }
    __syncthreads();
    float bv[GC]; int bi[GC];
    #pragma unroll
    for (int j = 0; j < GC; ++j) { bv[j] = -1e30f; bi[j] = 0; }
    for (int a = threadIdx.x; a < A_N; a += 256) {
        float4 an = reinterpret_cast<const float4*>(anchors)[a];
        float aa = fmaxf(an.z - an.x, 0.0f) * fmaxf(an.w - an.y, 0.0f);
        #pragma unroll
        for (int j = 0; j < GC; ++j) {
            // j >= ng reads uninitialized LDS; result never stored (harmless)
            float iou = iou_one(sg[j][0], sg[j][1], sg[j][2], sg[j][3], sg[j][4],
                                an.x, an.y, an.z, an.w, aa);
            if (iou > bv[j]) { bv[j] = iou; bi[j] = a; }   // strict > keeps smallest a
        }
    }
    __shared__ float sv[256];
    __shared__ int   si[256];
    for (int j = 0; j < ng; ++j) {         // ng uniform per block
        sv[threadIdx.x] = bv[j]; si[threadIdx.x] = bi[j];
        __syncthreads();
        for (int s = 128; s > 0; s >>= 1) {
            if (threadIdx.x < s) {
                float v2 = sv[threadIdx.x + s]; int i2 = si[threadIdx.x + s];
                float v1 = sv[threadIdx.x];     int i1 = si[threadIdx.x];
                if (v2 > v1 || (v2 == v1 && i2 < i1)) { sv[threadIdx.x] = v2; si[threadIdx.x] = i2; }
            }
            __syncthreads();
        }
        if (threadIdx.x == 0) bp_idx[b * G_N + g0 + j] = si[0];
        __syncthreads();
    }
}

// fused per-anchor pass: best-target argmax + force-match override + label +
// smooth-L1 loc loss + log-softmax (mining value + positive CE) + reductions
__global__ __launch_bounds__(256) void fused_kernel(
        const float* __restrict__ gts, const int* __restrict__ counts,
        const float* __restrict__ anchors, const float* __restrict__ pred_loc,
        const float* __restrict__ conf, const int* __restrict__ bp_idx,
        float* __restrict__ mining, float* __restrict__ loc_part,
        float* __restrict__ ce_part, int* __restrict__ num_pos_row) {
    int i = blockIdx.x * 256 + threadIdx.x;
    int b = blockIdx.x >> 7;               // 128 blocks per batch row
    int a = i & (A_N - 1);
    int cnt = counts[b];
    __shared__ float sg[G_N][5];           // x0,y0,x1,y1,area
    __shared__ int   sl[G_N];              // gt label
    __shared__ int   sp[G_N];              // forced prior index per g
    if (threadIdx.x < G_N) {
        int g = threadIdx.x;
        const float* gtb = gts + (size_t)(b * G_N + g) * 5;
        float x0 = gtb[0], y0 = gtb[1], x1 = gtb[2], y1 = gtb[3];
        sg[g][0] = x0; sg[g][1] = y0; sg[g][2] = x1; sg[g][3] = y1;
        sg[g][4] = fmaxf(x1 - x0, 0.0f) * fmaxf(y1 - y0, 0.0f);
        sl[g] = (int)gtb[4];
        sp[g] = bp_idx[b * G_N + g];       // garbage for g>=cnt, never used
    }
    __syncthreads();

    float4 an = reinterpret_cast<const float4*>(anchors)[a];
    float aa = fmaxf(an.z - an.x, 0.0f) * fmaxf(an.w - an.y, 0.0f);
    float best = -2.0f; int gi = 0;
    for (int g = 0; g < cnt; ++g) {
        float iou = iou_one(sg[g][0], sg[g][1], sg[g][2], sg[g][3], sg[g][4],
                            an.x, an.y, an.z, an.w, aa);
        if (iou > best) { best = iou; gi = g; }     // first occurrence = smallest g
    }
    // force-match override (ascending g, last-wins = scatter semantics)
    bool forced = false;
    for (int g = 0; g < cnt; ++g) {
        if (sp[g] == a) { gi = g; forced = true; }
    }
    float iou_eff = forced ? 2.0f : best;
    int label = 0;
    if (!(iou_eff < 0.5f)) label = sl[gi];
    bool pos = label > 0;

    // smooth-L1 localisation loss (positives only), exact ref FP order
    float contrib = 0.0f;
    if (pos) {
        float acx = (an.x + an.z) * 0.5f, acy = (an.y + an.w) * 0.5f;
        float aw = an.z - an.x, ah = an.w - an.y;
        float gx0 = sg[gi][0], gy0 = sg[gi][1], gx1 = sg[gi][2], gy1 = sg[gi][3];
        float cx = (gx0 + gx1) * 0.5f, cy = (gy0 + gy1) * 0.5f;
        float w = gx1 - gx0, h = gy1 - gy0;
        float l0 = ((cx - acx) / aw) / 0.1f;
        float l1 = ((cy - acy) / ah) / 0.1f;
        float l2 = logf(fmaxf(w / aw, 1e-8f)) / 0.2f;
        float l3 = logf(fmaxf(h / ah, 1e-8f)) / 0.2f;
        float4 p = reinterpret_cast<const float4*>(pred_loc)[i];
        float d0 = fabsf(p.x - l0), d1 = fabsf(p.y - l1);
        float d2 = fabsf(p.z - l2), d3 = fabsf(p.w - l3);
        contrib  = (d0 < 1.0f ? 0.5f * d0 * d0 : d0 - 0.5f);
        contrib += (d1 < 1.0f ? 0.5f * d1 * d1 : d1 - 0.5f);
        contrib += (d2 < 1.0f ? 0.5f * d2 * d2 : d2 - 0.5f);
        contrib += (d3 < 1.0f ? 0.5f * d3 * d3 : d3 - 0.5f);
    }

    // log-softmax, FP order mirrors jax.nn.log_softmax
    float v[C_N];
    const float2* c2 = reinterpret_cast<const float2*>(conf + (size_t)i * C_N);
    #pragma unroll
    for (int j = 0; j < C_N / 2; ++j) { float2 t = c2[j]; v[2 * j] = t.x; v[2 * j + 1] = t.y; }
    float m = v[0];
    #pragma unroll
    for (int j = 1; j < C_N; ++j) m = fmaxf(m, v[j]);
    float s = 0.0f;
    #pragma unroll
    for (int j = 0; j < C_N; ++j) s += expf(v[j] - m);
    float ls = logf(s);
    float ce_pos = 0.0f;
    if (pos) {
        float vl = v[0];
        #pragma unroll
        for (int j = 1; j < C_N; ++j) vl = (j == label) ? v[j] : vl;  // register select
        ce_pos = ls - (vl - m);
        mining[i] = __int_as_float(0xFF800000);  // -inf
    } else {
        mining[i] = ls - (v[0] - m);             // bg_loss
    }

    // block reduction: loc sum, pos CE sum, pos count
    unsigned long long bal = __ballot(pos);
    for (int o = 32; o > 0; o >>= 1) {
        contrib += __shfl_down(contrib, o, 64);
        ce_pos  += __shfl_down(ce_pos, o, 64);
    }
    __shared__ float swl[4], swc[4];
    __shared__ int   swi[4];
    int wid = threadIdx.x >> 6, lane = threadIdx.x & 63;
    if (lane == 0) { swl[wid] = contrib; swc[wid] = ce_pos; swi[wid] = __popcll(bal); }
    __syncthreads();
    if (threadIdx.x == 0) {
        float sL = swl[0] + swl[1] + swl[2] + swl[3];
        float sC = swc[0] + swc[1] + swc[2] + swc[3];
        int   c  = swi[0] + swi[1] + swi[2] + swi[3];
        int slot = blockIdx.x & 31;
        if (sL != 0.0f) atomicAdd(&loc_part[slot], sL);
        if (sC != 0.0f) atomicAdd(&ce_part[slot], sC);
        if (c) atomicAdd(&num_pos_row[b], c);
    }
}

// ---- radix select support: suffix-scan over packed-u16 histogram, pick bin + rank ----
__device__ __forceinline__ void scan_pick(unsigned* hist, int nwords,
                                          unsigned* sA, unsigned* sB,
                                          int krem, int* s_bin, int* s_krem) {
    int t = threadIdx.x;
    unsigned lo = 0, hi = 0;
    if (t < nwords) { unsigned w = hist[t]; lo = w & 0xFFFFu; hi = w >> 16; }
    sA[t] = lo + hi;
    __syncthreads();
    unsigned* src = sA; unsigned* dst = sB;
    for (int d = 1; d < 1024; d <<= 1) {
        unsigned vv = src[t] + ((t + d < 1024) ? src[t + d] : 0u);
        dst[t] = vv;
        __syncthreads();
        unsigned* tmp = src; src = dst; dst = tmp;
    }
    unsigned incl = src[t];
    unsigned incl_next = (t < 1023) ? src[t + 1] : 0u;
    unsigned uk = (unsigned)krem;
    if (incl >= uk && incl_next < uk) {     // unique crossing thread
        unsigned cum = incl_next;
        if (cum + hi >= uk) { *s_bin = 2 * t + 1; *s_krem = (int)(uk - cum); }
        else                { *s_bin = 2 * t;     *s_krem = (int)(uk - cum - hi); }
    }
    __syncthreads();
}

// per-row 3-level (11/11/10 bit) histogram select: sum of top-k bg_loss, k = 3*num_pos
__global__ __launch_bounds__(1024) void select_kernel(
        const float* __restrict__ mining, const int* __restrict__ num_pos_row,
        float* __restrict__ neg_sum) {
    int b = blockIdx.x;
    int tid = threadIdx.x;
    int np = num_pos_row[b];
    long long k = 3LL * np;
    int num_neg = A_N - np;
    int k_eff = (int)((k < (long long)num_neg) ? k : (long long)num_neg);
    if (k_eff <= 0) { if (tid == 0) neg_sum[b] = 0.0f; return; }   // uniform exit
    const float4* row4 = reinterpret_cast<const float4*>(mining + (size_t)b * A_N);

    __shared__ unsigned hist[1024];     // 2048 u16 bins packed
    __shared__ unsigned sA[1024], sB[1024];
    __shared__ unsigned surv[SEL_CAP];
    __shared__ int s_n1, s_bin, s_krem;
    __shared__ float swf[16];

    // ---- level 1: bits [31:21] (2048 bins) ----
    hist[tid] = 0;
    if (tid == 0) s_n1 = 0;
    __syncthreads();
    #pragma unroll
    for (int it = 0; it < A_N / 4 / 1024; ++it) {
        float4 vv = row4[tid + it * 1024];
        unsigned k0 = f2key(vv.x), k1 = f2key(vv.y), k2 = f2key(vv.z), k3 = f2key(vv.w);
        unsigned b0 = k0 >> 21, b1 = k1 >> 21, b2 = k2 >> 21, b3 = k3 >> 21;
        atomicAdd(&hist[b0 >> 1], (b0 & 1) ? 65536u : 1u);
        atomicAdd(&hist[b1 >> 1], (b1 & 1) ? 65536u : 1u);
        atomicAdd(&hist[b2 >> 1], (b2 & 1) ? 65536u : 1u);
        atomicAdd(&hist[b3 >> 1], (b3 & 1) ? 65536u : 1u);
    }
    __syncthreads();
    scan_pick(hist, 1024, sA, sB, k_eff, &s_bin, &s_krem);
    unsigned bin1 = (unsigned)s_bin;
    int krem1 = s_krem;
    __syncthreads();

    // ---- pass 2: sum strictly-above bins + collect survivors of bin1 ----
    float sum_sel = 0.0f;
    #pragma unroll
    for (int it = 0; it < A_N / 4 / 1024; ++it) {
        float4 vv = row4[tid + it * 1024];
        float xs[4] = {vv.x, vv.y, vv.z, vv.w};
        #pragma unroll
        for (int e = 0; e < 4; ++e) {
            unsigned key = f2key(xs[e]);
            unsigned t11 = key >> 21;
            if (t11 > bin1) sum_sel += xs[e];
            else if (t11 == bin1) {
                int p = atomicAdd(&s_n1, 1);
                if (p < SEL_CAP) surv[p] = key;
            }
        }
    }
    __syncthreads();
    int n1 = s_n1;
    bool in_lds = (n1 <= SEL_CAP);

    // ---- level 2: bits [20:10] among survivors ----
    hist[tid] = 0;
    __syncthreads();
    if (in_lds) {
        for (int ii = tid; ii < n1; ii += 1024) {
            unsigned bin = (surv[ii] >> 10) & 0x7FFu;
            atomicAdd(&hist[bin >> 1], (bin & 1) ? 65536u : 1u);
        }
    } else {
        for (int it = 0; it < A_N / 4 / 1024; ++it) {
            float4 vv = row4[tid + it * 1024];
            float xs[4] = {vv.x, vv.y, vv.z, vv.w};
            for (int e = 0; e < 4; ++e) {
                unsigned key = f2key(xs[e]);
                if ((key >> 21) == bin1) {
                    unsigned bin = (key >> 10) & 0x7FFu;
                    atomicAdd(&hist[bin >> 1], (bin & 1) ? 65536u : 1u);
                }
            }
        }
    }
    __syncthreads();
    scan_pick(hist, 1024, sA, sB, krem1, &s_bin, &s_krem);
    unsigned prefix22 = (bin1 << 11) | (unsigned)s_bin;
    int krem2 = s_krem;
    __syncthreads();

    // ---- level 3: bits [9:0] ----
    hist[tid] = 0;
    __syncthreads();
    if (in_lds) {
        for (int ii = tid; ii < n1; ii += 1024) {
            unsigned key = surv[ii];
            if ((key >> 10) == prefix22) {
                unsigned bin = key & 0x3FFu;
                atomicAdd(&hist[bin >> 1], (bin & 1) ? 65536u : 1u);
            }
        }
    } else {
        for (int it = 0; it < A_N / 4 / 1024; ++it) {
            float4 vv = row4[tid + it * 1024];
            float xs[4] = {vv.x, vv.y, vv.z, vv.w};
            for (int e = 0; e < 4; ++e) {
                unsigned key = f2key(xs[e]);
                if ((key >> 10) == prefix22) {
                    unsigned bin = key & 0x3FFu;
                    atomicAdd(&hist[bin >> 1], (bin & 1) ? 65536u : 1u);
                }
            }
        }
    }
    __syncthreads();
    scan_pick(hist, 512, sA, sB, krem2, &s_bin, &s_krem);
    unsigned kth = (prefix22 << 10) | (unsigned)s_bin;
    int krem3 = s_krem;
    __syncthreads();

    // ---- final: add survivors strictly above kth ----
    if (in_lds) {
        for (int ii = tid; ii < n1; ii += 1024) {
            unsigned key = surv[ii];
            if (key > kth) sum_sel += key2f(key);
        }
    } else {
        for (int it = 0; it < A_N / 4 / 1024; ++it) {
            float4 vv = row4[tid + it * 1024];
            float xs[4] = {vv.x, vv.y, vv.z, vv.w};
            for (int e = 0; e < 4; ++e) {
                unsigned key = f2key(xs[e]);
                if ((key >> 21) == bin1 && key > kth) sum_sel += xs[e];
            }
        }
    }
    for (int o = 32; o > 0; o >>= 1) sum_sel += __shfl_down(sum_sel, o, 64);
    int wid = tid >> 6, lane = tid & 63;
    if (lane == 0) swf[wid] = sum_sel;
    __syncthreads();
    if (tid == 0) {
        float tot = 0.0f;
        #pragma unroll
        for (int w = 0; w < 16; ++w) tot += swf[w];
        neg_sum[b] = tot + (float)krem3 * key2f(kth);   // ties share the identical value
    }
}

__global__ void final_kernel(const float* __restrict__ loc_part, const float* __restrict__ ce_part,
                             const int* __restrict__ num_pos_row, const float* __restrict__ neg_sum,
                             float* __restrict__ out) {
    if (threadIdx.x != 0) return;
    int tot = 0;
    for (int b = 0; b < B_N; ++b) tot += num_pos_row[b];
    float npos = fmaxf(1.0f, (float)tot);
    float L = 0.0f, Cp = 0.0f, Ng = 0.0f;
    for (int j = 0; j < B_N; ++j) { L += loc_part[j]; Cp += ce_part[j]; Ng += neg_sum[j]; }
    out[0] = L / (npos * 4.0f);          // localisation loss
    out[1] = (Cp + Ng) / (npos * 4.0f);  // classification loss
}

// ---------------- launch ----------------

extern "C" void kernel_launch(void* const* d_in, const int* in_sizes, int n_in,
                              void* d_out, int out_size, void* d_ws, size_t ws_size,
                              hipStream_t stream) {
    const float* conf     = (const float*)d_in[0];
    const float* pred_loc = (const float*)d_in[1];
    const float* gts      = (const float*)d_in[2];
    const int*   counts   = (const int*)d_in[3];
    const float* anchors  = (const float*)d_in[4];
    float* out = (float*)d_out;

    char* ws = (char*)d_ws;
    float* loc_part     = (float*)ws;                 // [0:32)
    float* ce_part      = (float*)(ws + 128);         // [32:64)
    int*   num_pos_row  = (int*)(ws + 256);           // [64:96)
    float* neg_sum      = (float*)(ws + 384);         // [96:128)
    int*   bp_idx       = (int*)(ws + 512);           // B*G ints (6400B)
    float* mining       = (float*)(ws + 8192);        // BA floats (4MB)

    init_kernel<<<1, 128, 0, stream>>>(loc_part);
    best_prior_kernel<<<B_N * NCHUNK, 256, 0, stream>>>(gts, counts, anchors, bp_idx);
    fused_kernel<<<BA / 256, 256, 0, stream>>>(gts, counts, anchors, pred_loc, conf, bp_idx,
                                               mining, loc_part, ce_part, num_pos_row);
    select_kernel<<<B_N, 1024, 0, stream>>>(mining, num_pos_row, neg_sum);
    final_kernel<<<1, 64, 0, stream>>>(loc_part, ce_part, num_pos_row, neg_sum, out);
}

// Round 6
// 253.386 us; speedup vs baseline: 1.9552x; 1.1889x over previous
//
#include <hip/hip_runtime.h>
#include <cstdint>
#include <cstddef>

#define B_N 32
#define A_N 32768
#define G_N 50
#define C_N 22
#define BA  (B_N * A_N)

#define GC 4
#define NCHUNK ((G_N + GC - 1) / GC)   // 13
#define ASEG 16                        // anchor segments
#define ASEG_LEN (A_N / ASEG)          // 2048

#define SEL_CAP 4096   // survivor list capacity (LDS); fallback to global rescan if exceeded

// ---------------- helpers ----------------

__device__ __forceinline__ float iou_one(float gx0, float gy0, float gx1, float gy1, float ga,
                                         float ax0, float ay0, float ax1, float ay1, float aa) {
    // mirror reference op order: inter / (a0 + a1 - inter + 1e-5)
    float lx = fmaxf(gx0, ax0), ly = fmaxf(gy0, ay0);
    float rx = fminf(gx1, ax1), ry = fminf(gy1, ay1);
    float iw = fmaxf(rx - lx, 0.0f), ih = fmaxf(ry - ly, 0.0f);
    float inter = iw * ih;
    return inter / (ga + aa - inter + 1e-5f);
}

__device__ __forceinline__ unsigned int f2key(float x) {
    unsigned int u = __float_as_uint(x);
    return (u & 0x80000000u) ? ~u : (u | 0x80000000u);
}

__device__ __forceinline__ float key2f(unsigned int k) {
    return __uint_as_float((k & 0x80000000u) ? (k & 0x7FFFFFFFu) : ~k);
}

// ---------------- kernels ----------------

// zero 128 header words + bp_best[B_N*G_N] u64
__global__ void init_kernel(float* hdr, unsigned long long* bp_best) {
    if (threadIdx.x < 128) hdr[threadIdx.x] = 0.0f;
    for (int i = threadIdx.x; i < B_N * G_N; i += 256) bp_best[i] = 0ull;
}

// block = (b, g-chunk of GC, anchor-segment): partial argmax over 2048 anchors
// for GC gts; combine via packed-u64 atomicMax (iou-key hi, ~a lo -> smallest a on ties)
__global__ __launch_bounds__(256) void best_prior_kernel(
        const float* __restrict__ gts, const int* __restrict__ counts,
        const float* __restrict__ anchors, unsigned long long* __restrict__ bp_best) {
    int blk = blockIdx.x;
    int b   = blk / (NCHUNK * ASEG);
    int rem = blk % (NCHUNK * ASEG);
    int ch  = rem / ASEG;
    int seg = rem % ASEG;
    int g0  = ch * GC;
    int cnt = counts[b];
    if (g0 >= cnt) return;                 // uniform exit
    // uniform (scalar) gt loads; zero-box for j >= valid count (iou=0, never stored)
    float gx0[GC], gy0[GC], gx1[GC], gy1[GC], ga[GC];
    #pragma unroll
    for (int j = 0; j < GC; ++j) {
        if (g0 + j < cnt) {
            const float* p = gts + (size_t)(b * G_N + g0 + j) * 5;
            gx0[j] = p[0]; gy0[j] = p[1]; gx1[j] = p[2]; gy1[j] = p[3];
            ga[j] = fmaxf(gx1[j] - gx0[j], 0.0f) * fmaxf(gy1[j] - gy0[j], 0.0f);
        } else { gx0[j] = 0.f; gy0[j] = 0.f; gx1[j] = 0.f; gy1[j] = 0.f; ga[j] = 0.f; }
    }
    unsigned long long best[GC];
    #pragma unroll
    for (int j = 0; j < GC; ++j) best[j] = 0ull;
    int a0 = seg * ASEG_LEN;
    for (int a = a0 + threadIdx.x; a < a0 + ASEG_LEN; a += 256) {
        float4 an = reinterpret_cast<const float4*>(anchors)[a];
        float aa = fmaxf(an.z - an.x, 0.0f) * fmaxf(an.w - an.y, 0.0f);
        #pragma unroll
        for (int j = 0; j < GC; ++j) {
            float iou = iou_one(gx0[j], gy0[j], gx1[j], gy1[j], ga[j],
                                an.x, an.y, an.z, an.w, aa);
            unsigned long long key = ((unsigned long long)f2key(iou) << 32) | (unsigned)(~a);
            if (key > best[j]) best[j] = key;
        }
    }
    // wave-level reduce (max of packed keys), then one atomic per wave per g
    #pragma unroll
    for (int j = 0; j < GC; ++j) {
        for (int o = 32; o > 0; o >>= 1) {
            unsigned long long other = __shfl_down(best[j], o, 64);
            if (other > best[j]) best[j] = other;
        }
    }
    if ((threadIdx.x & 63) == 0) {
        int ng = cnt - g0; if (ng > GC) ng = GC;
        for (int j = 0; j < ng; ++j)
            atomicMax(&bp_best[b * G_N + g0 + j], best[j]);
    }
}

// fused per-anchor pass: best-target argmax + force-match override + label +
// smooth-L1 loc loss + log-softmax (mining value + positive CE) + reductions
__global__ __launch_bounds__(256) void fused_kernel(
        const float* __restrict__ gts, const int* __restrict__ counts,
        const float* __restrict__ anchors, const float* __restrict__ pred_loc,
        const float* __restrict__ conf, const unsigned long long* __restrict__ bp_best,
        float* __restrict__ mining, float* __restrict__ loc_part,
        float* __restrict__ ce_part, int* __restrict__ num_pos_row) {
    int i = blockIdx.x * 256 + threadIdx.x;
    int b = blockIdx.x >> 7;               // 128 blocks per batch row
    int a = i & (A_N - 1);
    int cnt = counts[b];
    __shared__ float sg[G_N][5];           // x0,y0,x1,y1,area
    __shared__ int   sl[G_N];              // gt label
    __shared__ int   sp[G_N];              // forced prior index per g (-1 if none)
    if (threadIdx.x < G_N) {
        int g = threadIdx.x;
        const float* gtb = gts + (size_t)(b * G_N + g) * 5;
        float x0 = gtb[0], y0 = gtb[1], x1 = gtb[2], y1 = gtb[3];
        sg[g][0] = x0; sg[g][1] = y0; sg[g][2] = x1; sg[g][3] = y1;
        sg[g][4] = fmaxf(x1 - x0, 0.0f) * fmaxf(y1 - y0, 0.0f);
        sl[g] = (int)gtb[4];
        sp[g] = (int)(~(unsigned)(bp_best[b * G_N + g] & 0xFFFFFFFFull)); // -1 if unwritten
    }
    __syncthreads();

    float4 an = reinterpret_cast<const float4*>(anchors)[a];
    float aa = fmaxf(an.z - an.x, 0.0f) * fmaxf(an.w - an.y, 0.0f);
    float best = -2.0f; int gi = 0;
    for (int g = 0; g < cnt; ++g) {
        float iou = iou_one(sg[g][0], sg[g][1], sg[g][2], sg[g][3], sg[g][4],
                            an.x, an.y, an.z, an.w, aa);
        if (iou > best) { best = iou; gi = g; }     // first occurrence = smallest g
    }
    // force-match override (ascending g, last-wins = scatter semantics)
    bool forced = false;
    for (int g = 0; g < cnt; ++g) {
        if (sp[g] == a) { gi = g; forced = true; }
    }
    float iou_eff = forced ? 2.0f : best;
    int label = 0;
    if (!(iou_eff < 0.5f)) label = sl[gi];
    bool pos = label > 0;

    // smooth-L1 localisation loss (positives only), exact ref FP order
    float contrib = 0.0f;
    if (pos) {
        float acx = (an.x + an.z) * 0.5f, acy = (an.y + an.w) * 0.5f;
        float aw = an.z - an.x, ah = an.w - an.y;
        float gx0 = sg[gi][0], gy0 = sg[gi][1], gx1 = sg[gi][2], gy1 = sg[gi][3];
        float cx = (gx0 + gx1) * 0.5f, cy = (gy0 + gy1) * 0.5f;
        float w = gx1 - gx0, h = gy1 - gy0;
        float l0 = ((cx - acx) / aw) / 0.1f;
        float l1 = ((cy - acy) / ah) / 0.1f;
        float l2 = logf(fmaxf(w / aw, 1e-8f)) / 0.2f;
        float l3 = logf(fmaxf(h / ah, 1e-8f)) / 0.2f;
        float4 p = reinterpret_cast<const float4*>(pred_loc)[i];
        float d0 = fabsf(p.x - l0), d1 = fabsf(p.y - l1);
        float d2 = fabsf(p.z - l2), d3 = fabsf(p.w - l3);
        contrib  = (d0 < 1.0f ? 0.5f * d0 * d0 : d0 - 0.5f);
        contrib += (d1 < 1.0f ? 0.5f * d1 * d1 : d1 - 0.5f);
        contrib += (d2 < 1.0f ? 0.5f * d2 * d2 : d2 - 0.5f);
        contrib += (d3 < 1.0f ? 0.5f * d3 * d3 : d3 - 0.5f);
    }

    // log-softmax, FP order mirrors jax.nn.log_softmax
    float v[C_N];
    const float2* c2 = reinterpret_cast<const float2*>(conf + (size_t)i * C_N);
    #pragma unroll
    for (int j = 0; j < C_N / 2; ++j) { float2 t = c2[j]; v[2 * j] = t.x; v[2 * j + 1] = t.y; }
    float m = v[0];
    #pragma unroll
    for (int j = 1; j < C_N; ++j) m = fmaxf(m, v[j]);
    float s = 0.0f;
    #pragma unroll
    for (int j = 0; j < C_N; ++j) s += expf(v[j] - m);
    float ls = logf(s);
    float ce_pos = 0.0f;
    if (pos) {
        float vl = v[0];
        #pragma unroll
        for (int j = 1; j < C_N; ++j) vl = (j == label) ? v[j] : vl;  // register select
        ce_pos = ls - (vl - m);
        mining[i] = __int_as_float(0xFF800000);  // -inf
    } else {
        mining[i] = ls - (v[0] - m);             // bg_loss
    }

    // block reduction: loc sum, pos CE sum, pos count
    unsigned long long bal = __ballot(pos);
    for (int o = 32; o > 0; o >>= 1) {
        contrib += __shfl_down(contrib, o, 64);
        ce_pos  += __shfl_down(ce_pos, o, 64);
    }
    __shared__ float swl[4], swc[4];
    __shared__ int   swi[4];
    int wid = threadIdx.x >> 6, lane = threadIdx.x & 63;
    if (lane == 0) { swl[wid] = contrib; swc[wid] = ce_pos; swi[wid] = __popcll(bal); }
    __syncthreads();
    if (threadIdx.x == 0) {
        float sL = swl[0] + swl[1] + swl[2] + swl[3];
        float sC = swc[0] + swc[1] + swc[2] + swc[3];
        int   c  = swi[0] + swi[1] + swi[2] + swi[3];
        int slot = blockIdx.x & 31;
        if (sL != 0.0f) atomicAdd(&loc_part[slot], sL);
        if (sC != 0.0f) atomicAdd(&ce_part[slot], sC);
        if (c) atomicAdd(&num_pos_row[b], c);
    }
}

// ---- radix select support: suffix-scan over packed-u16 histogram, pick bin + rank ----
__device__ __forceinline__ void scan_pick(unsigned* hist, int nwords,
                                          unsigned* sA, unsigned* sB,
                                          int krem, int* s_bin, int* s_krem) {
    int t = threadIdx.x;
    unsigned lo = 0, hi = 0;
    if (t < nwords) { unsigned w = hist[t]; lo = w & 0xFFFFu; hi = w >> 16; }
    sA[t] = lo + hi;
    __syncthreads();
    unsigned* src = sA; unsigned* dst = sB;
    for (int d = 1; d < 1024; d <<= 1) {
        unsigned vv = src[t] + ((t + d < 1024) ? src[t + d] : 0u);
        dst[t] = vv;
        __syncthreads();
        unsigned* tmp = src; src = dst; dst = tmp;
    }
    unsigned incl = src[t];
    unsigned incl_next = (t < 1023) ? src[t + 1] : 0u;
    unsigned uk = (unsigned)krem;
    if (incl >= uk && incl_next < uk) {     // unique crossing thread
        unsigned cum = incl_next;
        if (cum + hi >= uk) { *s_bin = 2 * t + 1; *s_krem = (int)(uk - cum); }
        else                { *s_bin = 2 * t;     *s_krem = (int)(uk - cum - hi); }
    }
    __syncthreads();
}

// per-row 3-level (11/11/10 bit) histogram select: sum of top-k bg_loss, k = 3*num_pos
__global__ __launch_bounds__(1024) void select_kernel(
        const float* __restrict__ mining, const int* __restrict__ num_pos_row,
        float* __restrict__ neg_sum) {
    int b = blockIdx.x;
    int tid = threadIdx.x;
    int np = num_pos_row[b];
    long long k = 3LL * np;
    int num_neg = A_N - np;
    int k_eff = (int)((k < (long long)num_neg) ? k : (long long)num_neg);
    if (k_eff <= 0) { if (tid == 0) neg_sum[b] = 0.0f; return; }   // uniform exit
    const float4* row4 = reinterpret_cast<const float4*>(mining + (size_t)b * A_N);

    __shared__ unsigned hist[1024];     // 2048 u16 bins packed
    __shared__ unsigned sA[1024], sB[1024];
    __shared__ unsigned surv[SEL_CAP];
    __shared__ int s_n1, s_bin, s_krem;
    __shared__ float swf[16];

    // ---- level 1: bits [31:21] (2048 bins) ----
    hist[tid] = 0;
    if (tid == 0) s_n1 = 0;
    __syncthreads();
    #pragma unroll
    for (int it = 0; it < A_N / 4 / 1024; ++it) {
        float4 vv = row4[tid + it * 1024];
        unsigned k0 = f2key(vv.x), k1 = f2key(vv.y), k2 = f2key(vv.z), k3 = f2key(vv.w);
        unsigned b0 = k0 >> 21, b1 = k1 >> 21, b2 = k2 >> 21, b3 = k3 >> 21;
        atomicAdd(&hist[b0 >> 1], (b0 & 1) ? 65536u : 1u);
        atomicAdd(&hist[b1 >> 1], (b1 & 1) ? 65536u : 1u);
        atomicAdd(&hist[b2 >> 1], (b2 & 1) ? 65536u : 1u);
        atomicAdd(&hist[b3 >> 1], (b3 & 1) ? 65536u : 1u);
    }
    __syncthreads();
    scan_pick(hist, 1024, sA, sB, k_eff, &s_bin, &s_krem);
    unsigned bin1 = (unsigned)s_bin;
    int krem1 = s_krem;
    __syncthreads();

    // ---- pass 2: sum strictly-above bins + collect survivors of bin1 ----
    float sum_sel = 0.0f;
    #pragma unroll
    for (int it = 0; it < A_N / 4 / 1024; ++it) {
        float4 vv = row4[tid + it * 1024];
        float xs[4] = {vv.x, vv.y, vv.z, vv.w};
        #pragma unroll
        for (int e = 0; e < 4; ++e) {
            unsigned key = f2key(xs[e]);
            unsigned t11 = key >> 21;
            if (t11 > bin1) sum_sel += xs[e];
            else if (t11 == bin1) {
                int p = atomicAdd(&s_n1, 1);
                if (p < SEL_CAP) surv[p] = key;
            }
        }
    }
    __syncthreads();
    int n1 = s_n1;
    bool in_lds = (n1 <= SEL_CAP);

    // ---- level 2: bits [20:10] among survivors ----
    hist[tid] = 0;
    __syncthreads();
    if (in_lds) {
        for (int ii = tid; ii < n1; ii += 1024) {
            unsigned bin = (surv[ii] >> 10) & 0x7FFu;
            atomicAdd(&hist[bin >> 1], (bin & 1) ? 65536u : 1u);
        }
    } else {
        for (int it = 0; it < A_N / 4 / 1024; ++it) {
            float4 vv = row4[tid + it * 1024];
            float xs[4] = {vv.x, vv.y, vv.z, vv.w};
            for (int e = 0; e < 4; ++e) {
                unsigned key = f2key(xs[e]);
                if ((key >> 21) == bin1) {
                    unsigned bin = (key >> 10) & 0x7FFu;
                    atomicAdd(&hist[bin >> 1], (bin & 1) ? 65536u : 1u);
                }
            }
        }
    }
    __syncthreads();
    scan_pick(hist, 1024, sA, sB, krem1, &s_bin, &s_krem);
    unsigned prefix22 = (bin1 << 11) | (unsigned)s_bin;
    int krem2 = s_krem;
    __syncthreads();

    // ---- level 3: bits [9:0] ----
    hist[tid] = 0;
    __syncthreads();
    if (in_lds) {
        for (int ii = tid; ii < n1; ii += 1024) {
            unsigned key = surv[ii];
            if ((key >> 10) == prefix22) {
                unsigned bin = key & 0x3FFu;
                atomicAdd(&hist[bin >> 1], (bin & 1) ? 65536u : 1u);
            }
        }
    } else {
        for (int it = 0; it < A_N / 4 / 1024; ++it) {
            float4 vv = row4[tid + it * 1024];
            float xs[4] = {vv.x, vv.y, vv.z, vv.w};
            for (int e = 0; e < 4; ++e) {
                unsigned key = f2key(xs[e]);
                if ((key >> 10) == prefix22) {
                    unsigned bin = key & 0x3FFu;
                    atomicAdd(&hist[bin >> 1], (bin & 1) ? 65536u : 1u);
                }
            }
        }
    }
    __syncthreads();
    scan_pick(hist, 512, sA, sB, krem2, &s_bin, &s_krem);
    unsigned kth = (prefix22 << 10) | (unsigned)s_bin;
    int krem3 = s_krem;
    __syncthreads();

    // ---- final: add survivors strictly above kth ----
    if (in_lds) {
        for (int ii = tid; ii < n1; ii += 1024) {
            unsigned key = surv[ii];
            if (key > kth) sum_sel += key2f(key);
        }
    } else {
        for (int it = 0; it < A_N / 4 / 1024; ++it) {
            float4 vv = row4[tid + it * 1024];
            float xs[4] = {vv.x, vv.y, vv.z, vv.w};
            for (int e = 0; e < 4; ++e) {
                unsigned key = f2key(xs[e]);
                if ((key >> 21) == bin1 && key > kth) sum_sel += xs[e];
            }
        }
    }
    for (int o = 32; o > 0; o >>= 1) sum_sel += __shfl_down(sum_sel, o, 64);
    int wid = tid >> 6, lane = tid & 63;
    if (lane == 0) swf[wid] = sum_sel;
    __syncthreads();
    if (tid == 0) {
        float tot = 0.0f;
        #pragma unroll
        for (int w = 0; w < 16; ++w) tot += swf[w];
        neg_sum[b] = tot + (float)krem3 * key2f(kth);   // ties share the identical value
    }
}

__global__ void final_kernel(const float* __restrict__ loc_part, const float* __restrict__ ce_part,
                             const int* __restrict__ num_pos_row, const float* __restrict__ neg_sum,
                             float* __restrict__ out) {
    if (threadIdx.x != 0) return;
    int tot = 0;
    for (int b = 0; b < B_N; ++b) tot += num_pos_row[b];
    float npos = fmaxf(1.0f, (float)tot);
    float L = 0.0f, Cp = 0.0f, Ng = 0.0f;
    for (int j = 0; j < B_N; ++j) { L += loc_part[j]; Cp += ce_part[j]; Ng += neg_sum[j]; }
    out[0] = L / (npos * 4.0f);          // localisation loss
    out[1] = (Cp + Ng) / (npos * 4.0f);  // classification loss
}

// ---------------- launch ----------------

extern "C" void kernel_launch(void* const* d_in, const int* in_sizes, int n_in,
                              void* d_out, int out_size, void* d_ws, size_t ws_size,
                              hipStream_t stream) {
    const float* conf     = (const float*)d_in[0];
    const float* pred_loc = (const float*)d_in[1];
    const float* gts      = (const float*)d_in[2];
    const int*   counts   = (const int*)d_in[3];
    const float* anchors  = (const float*)d_in[4];
    float* out = (float*)d_out;

    char* ws = (char*)d_ws;
    float* loc_part     = (float*)ws;                 // [0:32)
    float* ce_part      = (float*)(ws + 128);         // [32:64)
    int*   num_pos_row  = (int*)(ws + 256);           // [64:96)
    float* neg_sum      = (float*)(ws + 384);         // [96:128)
    unsigned long long* bp_best = (unsigned long long*)(ws + 512);  // B*G u64 (12.8KB)
    float* mining       = (float*)(ws + 16384);       // BA floats (4MB)

    init_kernel<<<1, 256, 0, stream>>>(loc_part, bp_best);
    best_prior_kernel<<<B_N * NCHUNK * ASEG, 256, 0, stream>>>(gts, counts, anchors, bp_best);
    fused_kernel<<<BA / 256, 256, 0, stream>>>(gts, counts, anchors, pred_loc, conf, bp_best,
                                               mining, loc_part, ce_part, num_pos_row);
    select_kernel<<<B_N, 1024, 0, stream>>>(mining, num_pos_row, neg_sum);
    final_kernel<<<1, 64, 0, stream>>>(loc_part, ce_part, num_pos_row, neg_sum, out);
}